// Round 7
// baseline (391.215 us; speedup 1.0000x reference)
//
#include <hip/hip_runtime.h>

typedef unsigned short u16;
typedef __attribute__((ext_vector_type(8))) short short8;
typedef __attribute__((ext_vector_type(4))) float floatx4;
typedef __attribute__((ext_vector_type(4))) unsigned short ushort4v;

__device__ __forceinline__ float bf2f(u16 v){
  union { unsigned int u; float f; } x; x.u = ((unsigned int)v) << 16; return x.f;
}
__device__ __forceinline__ u16 f2bf(float f){
  union { float f; unsigned int u; } x; x.f = f;
  unsigned int r = x.u + 0x7FFFu + ((x.u >> 16) & 1u);
  return (u16)(r >> 16);
}
__device__ __forceinline__ short8 cvt8(float4 f0, float4 f1){
  short8 v;
  v[0] = (short)f2bf(f0.x); v[1] = (short)f2bf(f0.y);
  v[2] = (short)f2bf(f0.z); v[3] = (short)f2bf(f0.w);
  v[4] = (short)f2bf(f1.x); v[5] = (short)f2bf(f1.y);
  v[6] = (short)f2bf(f1.z); v[7] = (short)f2bf(f1.w);
  return v;
}

__device__ __forceinline__ void async16(const void* g, void* l){
  __builtin_amdgcn_global_load_lds(
      (__attribute__((address_space(1))) unsigned int*)const_cast<void*>(g),
      (__attribute__((address_space(3))) unsigned int*)l, 16, 0, 0);
}

// -------- fp32 -> bf16 bulk convert (memory-bound) --------------------------
__global__ __launch_bounds__(256)
void conv_bf16(const float* __restrict__ in, u16* __restrict__ out, int n8){
  const int stride = gridDim.x * 256;
  for (int i = blockIdx.x * 256 + threadIdx.x; i < n8; i += stride){
    float4 f0 = ((const float4*)in)[(size_t)i * 2];
    float4 f1 = ((const float4*)in)[(size_t)i * 2 + 1];
    *(short8*)(out + (size_t)i * 8) = cvt8(f0, f1);
  }
}

// -------- weight transpose: fp32 in [R][C] -> bf16 out [C][R] ---------------
__global__ void transpose_f32(const float* __restrict__ in, u16* __restrict__ out,
                              int R, int C){
  __shared__ u16 t[32][33];
  const int tx = threadIdx.x;
  const int c0 = blockIdx.x * 32, r0 = blockIdx.y * 32;
  for (int i = tx; i < 1024; i += 256){
    int r = i >> 5, c = i & 31;
    t[r][c] = f2bf(in[(size_t)(r0 + r) * C + c0 + c]);
  }
  __syncthreads();
  for (int i = tx; i < 1024; i += 256){
    int r = i >> 5, c = i & 31;
    out[(size_t)(c0 + r) * R + r0 + c] = t[c][r];
  }
}

// -------- expand relative-position bias -------------------------------------
// Layout [h][q][k] (q-major), values pre-scaled x8 (exact exponent shift):
//   0.125*(qk_raw + 8*b) == 0.125*qk_raw + b   (bit-identical)
__global__ void bias_expand(const float* __restrict__ table, u16* __restrict__ Bm){
  int i = blockIdx.x * 256 + threadIdx.x;   // 65536 (q,k) pairs, q major
  int q = i >> 8, k = i & 255;
  int rh = (q >> 4) - (k >> 4) + 15;
  int rw = (q & 15) - (k & 15) + 15;
  int idx = rh * 31 + rw;                   // [0, 960]
  #pragma unroll
  for (int h = 0; h < 8; h++)
    Bm[h * 65536 + i] = f2bf(8.0f * table[(size_t)idx * 8 + h]);
}

// ---------------- GEMM: C[M,N] = A[M,512] x Bt[N,512]^T ---------------------
// R7: 256x128 tile, BK=32 (was 64), 8 waves, 3 LDS slots = 72 KB -> TWO
// blocks/CU co-resident (16 waves/CU): while one block sits at its
// barrier/vmcnt wait the other computes — the cross-block overlap the 144 KB
// version (1 block/CU, MfmaUtil 16%) could not get. Counted-vmcnt pipeline
// unchanged in spirit: 3 loads/tile, wait vmcnt(3), never 0 until last iter.
// Bank swizzle for 4-chunk rows: XOR with (row>>1)&3 (16-lane fragment read
// spans 8 distinct 4-bank groups -> 2-way = free).
// MODE 0: write Q permuted [b][h][n][d] (bf16)
// MODE 1: write K [b][h][n][d] and V^T [b][h][d][n] (bf16)
// MODE 2: write fp32 out[row][col] = v + proj_b[col]
template<int MODE, int GX>
__global__ __launch_bounds__(512)
void gemm_bt(const u16* __restrict__ A, const u16* __restrict__ Bt,
             void* __restrict__ O0, u16* __restrict__ O1,
             const float* __restrict__ bias)
{
  __shared__ __align__(16) u16 As[3][256 * 32];   // 48 KB
  __shared__ __align__(16) u16 Bs[3][128 * 32];   // 24 KB
  const int tid  = threadIdx.x;
  const int lane = tid & 63, wave = tid >> 6;
  const int q16  = lane & 15, quad = lane >> 4;
  const int wr   = wave >> 1, wc = wave & 1;      // 4M x 2N wave tiles (64x64)

  constexpr int NWG = 128 * GX;
  constexpr int CPX = NWG / 8;
  const int bid = blockIdx.x;
  const int swz = (bid & 7) * CPX + (bid >> 3);   // bijective XCD swizzle
  const int rowBase = (swz / GX) * 256;
  const int colBase = (swz % GX) * 128;

  const u16* Ap = A  + (size_t)rowBase * 512;
  const u16* Bp = Bt + (size_t)colBase * 512;

  floatx4 acc[4][4];
  #pragma unroll
  for (int i = 0; i < 4; i++)
    #pragma unroll
    for (int j = 0; j < 4; j++) acc[i][j] = floatx4{0.f, 0.f, 0.f, 0.f};

  // staging geometry: granule g (16B) -> tile row g>>2, phys chunk g&3,
  // source chunk = phys ^ ((row>>1)&3)
  int sraA[2], scaA[2];
  #pragma unroll
  for (int j = 0; j < 2; j++){
    int g = tid + j * 512;
    sraA[j] = g >> 2;
    scaA[j] = ((g & 3) ^ ((sraA[j] >> 1) & 3)) * 8;
  }
  const int srB = tid >> 2;
  const int scB = ((tid & 3) ^ ((srB >> 1) & 3)) * 8;

  // per-tile staging: A = 2 async16/thread, B = 1 async16/thread (3 vmem ops)
  auto STAGE = [&](int slot, int kt){
    #pragma unroll
    for (int j = 0; j < 2; j++){
      u16* d = &As[slot][(size_t)(j * 512 + wave * 64) * 8];
      async16(Ap + (size_t)sraA[j] * 512 + kt * 32 + scaA[j], d);
    }
    u16* d = &Bs[slot][(size_t)(wave * 64) * 8];
    async16(Bp + (size_t)srB * 512 + kt * 32 + scB, d);
  };

  // prologue: two tiles in flight (6 outstanding vmem ops)
  STAGE(0, 0);
  STAGE(1, 1);

  #pragma unroll
  for (int kt = 0; kt < 16; kt++){                // K=512, BK=32
    const int cs = kt % 3;
    // tile kt complete when all but the newest 3 (tile kt+1) have retired
    if (kt < 15) asm volatile("s_waitcnt vmcnt(3)" ::: "memory");
    else         asm volatile("s_waitcnt vmcnt(0)" ::: "memory");
    __builtin_amdgcn_s_barrier();                 // publish slot cs; all waves
    __builtin_amdgcn_sched_barrier(0);            // done reading (kt+2)%3
    if (kt + 2 < 16) STAGE((kt + 2) % 3, kt + 2); // fill the freed slot
    __builtin_amdgcn_sched_barrier(0);            // pin issue-early

    __builtin_amdgcn_s_setprio(1);
    short8 af[4], bfr[4];
    #pragma unroll
    for (int mt = 0; mt < 4; mt++){
      int r  = wr * 64 + mt * 16 + q16;
      int ph = ((quad ^ ((r >> 1) & 3))) * 8;
      af[mt] = *(const short8*)(&As[cs][r * 32 + ph]);
    }
    #pragma unroll
    for (int nt = 0; nt < 4; nt++){
      int r  = wc * 64 + nt * 16 + q16;
      int ph = ((quad ^ ((r >> 1) & 3))) * 8;
      bfr[nt] = *(const short8*)(&Bs[cs][r * 32 + ph]);
    }
    #pragma unroll
    for (int mt = 0; mt < 4; mt++)
      #pragma unroll
      for (int nt = 0; nt < 4; nt++)
        acc[mt][nt] = __builtin_amdgcn_mfma_f32_16x16x32_bf16(
            af[mt], bfr[nt], acc[mt][nt], 0, 0, 0);
    __builtin_amdgcn_s_setprio(0);
  }

  #pragma unroll
  for (int mt = 0; mt < 4; mt++){
    #pragma unroll
    for (int nt = 0; nt < 4; nt++){
      const floatx4 v = acc[mt][nt];
      const int col = colBase + wc * 64 + nt * 16 + q16;
      #pragma unroll
      for (int r = 0; r < 4; r++){
        const int row = rowBase + wr * 64 + mt * 16 + quad * 4 + r;
        if (MODE == 0){
          int bb = row >> 8, n = row & 255, hh = col >> 6, dd = col & 63;
          ((u16*)O0)[(((size_t)(bb * 8 + hh)) * 256 + n) * 64 + dd] = f2bf(v[r]);
        } else if (MODE == 1){
          int bb = row >> 8, key = row & 255;
          int two = col >> 9, hh = (col >> 6) & 7, dd = col & 63;
          if (two == 0)
            ((u16*)O0)[(((size_t)(bb * 8 + hh)) * 256 + key) * 64 + dd] = f2bf(v[r]);
          else
            O1[(((size_t)(bb * 8 + hh)) * 64 + dd) * 256 + key] = f2bf(v[r]);
        } else {
          ((float*)O0)[(size_t)row * 512 + col] = v[r] + bias[col];
        }
      }
    }
  }
}

// ---------------- fused MFMA attention: one block per (b,h) -----------------
// R6 (kept): swapped-operand QK^T — acc[kt] = mfma(K_frag, Q_frag): each lane
// holds S[k = kt*16+quad*4+r][q = qbase+q16]. Softmax fully in-register:
// tree max/sum + 2 shfl_xor. P packed via v_cvt_pk_bf16_f32, redistributed
// to PV A-fragments with 8 shfl per K-step. No P LDS: Ks 32K + Vs 32K = 64K.
__global__ __launch_bounds__(512)
void attn_kernel(const u16* __restrict__ Qb, const u16* __restrict__ Kb,
                 const u16* __restrict__ Vtb, const u16* __restrict__ Bm,
                 u16* __restrict__ Ob)
{
  __shared__ __align__(16) u16 Ks[256 * 64];    // [k][d], 16B-chunk XOR swizzle
  __shared__ __align__(16) u16 Vs[64 * 256];    // [d][k], 16B-chunk XOR swizzle
  const int bh = blockIdx.x;
  const int b = bh >> 3, h = bh & 7;
  const u16* Qp = Qb  + (size_t)bh * 256 * 64;
  const u16* Kp = Kb  + (size_t)bh * 256 * 64;
  const u16* Vp = Vtb + (size_t)bh * 64 * 256;
  const u16* Bp = Bm  + (size_t)h * 65536;      // [q][k], pre-scaled x8
  const int tid = threadIdx.x;
  const int lane = tid & 63, wave = tid >> 6;
  const int q16 = lane & 15, quad = lane >> 4;

  // ---- stage K: 2048 granules of 16B; LDS linear, source pre-swizzled ----
  #pragma unroll
  for (int j = 0; j < 4; j++){
    int g = tid + j * 512;
    int row = g >> 3, phys = g & 7;             // 8 chunks per 64-elem row
    async16(Kp + row * 64 + ((phys ^ (row & 7)) * 8),
            &Ks[(size_t)(j * 512 + wave * 64) * 8]);
  }
  // ---- stage V: rows of 32 chunks ----
  #pragma unroll
  for (int j = 0; j < 4; j++){
    int g = tid + j * 512;
    int row = g >> 5, phys = g & 31;
    async16(Vp + row * 256 + ((phys ^ (row & 7)) * 8),
            &Vs[(size_t)(j * 512 + wave * 64) * 8]);
  }
  asm volatile("s_waitcnt vmcnt(4)" ::: "memory");  // this wave's K retired
  __builtin_amdgcn_s_barrier();                     // K visible to all waves

  // P-redistribution lane geometry (exchange among the 4 lanes sharing q16):
  // target quad t, step s needs words W[src quad' = 2(t&1)(+1)][kt = 2s+(t>>1)]
  const int la = q16 + ((quad & 1) << 5);       // lane of src quad' = 2(t&1)
  const int lb = la + 16;                       // lane of src quad' = 2(t&1)+1
  const bool hi = (quad >> 1) != 0;             // kt = 2s+1 half?

  for (int chunk = 0; chunk < 2; chunk++){
    const int qbase = wave * 32 + chunk * 16;
    const int qrow  = qbase + q16;
    const short8 qa0 = *(const short8*)(Qp + qrow * 64 + quad * 8);
    const short8 qa1 = *(const short8*)(Qp + qrow * 64 + 32 + quad * 8);

    // acc init = 8*bias at (q = qrow, k = kt*16 + quad*4 + r), r contiguous
    floatx4 acc[16];
    #pragma unroll
    for (int kt = 0; kt < 16; kt++){
      ushort4v bv = *(const ushort4v*)(Bp + (size_t)qrow * 256 + kt * 16 + quad * 4);
      floatx4 a;
      a[0] = bf2f(bv[0]); a[1] = bf2f(bv[1]);
      a[2] = bf2f(bv[2]); a[3] = bf2f(bv[3]);
      acc[kt] = a;
    }

    __builtin_amdgcn_s_setprio(1);
    #pragma unroll
    for (int kt = 0; kt < 16; kt++){
      const int row = kt * 16 + q16;
      const short8 k0 = *(const short8*)(&Ks[row * 64 + ((quad       ^ (row & 7)) * 8)]);
      const short8 k1 = *(const short8*)(&Ks[row * 64 + (((quad + 4) ^ (row & 7)) * 8)]);
      acc[kt] = __builtin_amdgcn_mfma_f32_16x16x32_bf16(k0, qa0, acc[kt], 0, 0, 0);
      acc[kt] = __builtin_amdgcn_mfma_f32_16x16x32_bf16(k1, qa1, acc[kt], 0, 0, 0);
    }
    __builtin_amdgcn_s_setprio(0);

    // ---- in-register row softmax (q fixed per lane) ----
    floatx4 m4 = acc[0];
    #pragma unroll
    for (int kt = 1; kt < 16; kt++){
      m4[0] = fmaxf(m4[0], acc[kt][0]);
      m4[1] = fmaxf(m4[1], acc[kt][1]);
      m4[2] = fmaxf(m4[2], acc[kt][2]);
      m4[3] = fmaxf(m4[3], acc[kt][3]);
    }
    float m = fmaxf(fmaxf(m4[0], m4[1]), fmaxf(m4[2], m4[3]));
    m = fmaxf(m, __shfl_xor(m, 16, 64));
    m = fmaxf(m, __shfl_xor(m, 32, 64));

    const float Cf = 0.125f * 1.4426950408889634f;   // scale * log2(e)
    unsigned int w[32];                              // packed bf16 pairs
    floatx4 l4 = {0.f, 0.f, 0.f, 0.f};
    #pragma unroll
    for (int kt = 0; kt < 16; kt++){
      float e0 = exp2f((acc[kt][0] - m) * Cf);
      float e1 = exp2f((acc[kt][1] - m) * Cf);
      float e2 = exp2f((acc[kt][2] - m) * Cf);
      float e3 = exp2f((acc[kt][3] - m) * Cf);
      l4[0] += e0; l4[1] += e1; l4[2] += e2; l4[3] += e3;
      asm("v_cvt_pk_bf16_f32 %0, %1, %2" : "=v"(w[2 * kt])     : "v"(e0), "v"(e1));
      asm("v_cvt_pk_bf16_f32 %0, %1, %2" : "=v"(w[2 * kt + 1]) : "v"(e2), "v"(e3));
    }
    float l = (l4[0] + l4[1]) + (l4[2] + l4[3]);
    l += __shfl_xor(l, 16, 64);
    l += __shfl_xor(l, 32, 64);
    const float rl = 1.0f / l;

    if (chunk == 0){
      asm volatile("s_waitcnt vmcnt(0)" ::: "memory"); // this wave's V retired
      __builtin_amdgcn_s_barrier();                    // V visible to all waves
    }

    // ---- PV: build A-fragment per 32-k step via 8 shfl, 4 mfma each ----
    floatx4 o[4];
    #pragma unroll
    for (int nt = 0; nt < 4; nt++) o[nt] = floatx4{0.f, 0.f, 0.f, 0.f};
    #pragma unroll
    for (int s = 0; s < 8; s++){
      int a0 = __shfl((int)w[4 * s + 0], la, 64);
      int a1 = __shfl((int)w[4 * s + 1], la, 64);
      int A0 = __shfl((int)w[4 * s + 2], la, 64);
      int A1 = __shfl((int)w[4 * s + 3], la, 64);
      int b0 = __shfl((int)w[4 * s + 0], lb, 64);
      int b1 = __shfl((int)w[4 * s + 1], lb, 64);
      int B0 = __shfl((int)w[4 * s + 2], lb, 64);
      int B1 = __shfl((int)w[4 * s + 3], lb, 64);
      union { int u[4]; short8 s8; } P;
      P.u[0] = hi ? A0 : a0;     // k = 32s + quad*8 + 0,1
      P.u[1] = hi ? A1 : a1;     // +2,3
      P.u[2] = hi ? B0 : b0;     // +4,5
      P.u[3] = hi ? B1 : b1;     // +6,7
      __builtin_amdgcn_s_setprio(1);
      #pragma unroll
      for (int nt = 0; nt < 4; nt++){
        const int row = nt * 16 + q16;
        const int c32 = s * 4 + quad;                  // 16B chunk in V row
        const short8 vb = *(const short8*)(&Vs[row * 256 + ((c32 ^ (row & 7)) * 8)]);
        o[nt] = __builtin_amdgcn_mfma_f32_16x16x32_bf16(P.s8, vb, o[nt], 0, 0, 0);
      }
      __builtin_amdgcn_s_setprio(0);
    }

    // rl lives at lane q16 = q-row; PV output rows are q = qbase+quad*4+r
    float rlr[4];
    #pragma unroll
    for (int r = 0; r < 4; r++) rlr[r] = __shfl(rl, quad * 4 + r, 64);
    #pragma unroll
    for (int nt = 0; nt < 4; nt++)
      #pragma unroll
      for (int r = 0; r < 4; r++){
        int q = qbase + quad * 4 + r;
        Ob[((size_t)(b * 256 + q)) * 512 + h * 64 + nt * 16 + q16] =
            f2bf(o[nt][r] * rlr[r]);
      }
  }
}

extern "C" void kernel_launch(void* const* d_in, const int* in_sizes, int n_in,
                              void* d_out, int out_size, void* d_ws, size_t ws_size,
                              hipStream_t stream)
{
  (void)in_sizes; (void)n_in; (void)out_size; (void)ws_size;
  const float* x      = (const float*)d_in[0];
  const float* y      = (const float*)d_in[1];
  const float* q_w    = (const float*)d_in[2];
  const float* kv_w   = (const float*)d_in[3];
  const float* proj_w = (const float*)d_in[4];
  const float* proj_b = (const float*)d_in[5];
  const float* btab   = (const float*)d_in[6];
  float* out = (float*)d_out;                   // fp32 output per reference
  char* w = (char*)d_ws;

  // workspace layout (total 137,363,456 B)
  u16* Qb   = (u16*)(w);                    // [B,H,256,64] bf16
  u16* Kb   = (u16*)(w + 33554432);         // [B,H,256,64]
  u16* Vtb  = (u16*)(w + 67108864);         // [B,H,64,256]
  u16* Ab   = (u16*)(w + 100663296);        // [B*N,512] bf16 (xb / yb / attn-out)
  u16* qwT  = (u16*)(w + 134217728);        // [512,512]
  u16* kvwT = (u16*)(w + 134742016);        // [1024,512]
  u16* pwT  = (u16*)(w + 135790592);        // [512,512]
  u16* Bm   = (u16*)(w + 136314880);        // [8,256,256] (x8, [h][q][k])

  transpose_f32<<<dim3(16, 16), 256, 0, stream>>>(q_w,    qwT,  512, 512);
  transpose_f32<<<dim3(32, 16), 256, 0, stream>>>(kv_w,   kvwT, 512, 1024);
  transpose_f32<<<dim3(16, 16), 256, 0, stream>>>(proj_w, pwT,  512, 512);
  bias_expand<<<dim3(256), 256, 0, stream>>>(btab, Bm);

  conv_bf16<<<dim3(2048), 256, 0, stream>>>(x, Ab, 2097152);
  gemm_bt<0, 4><<<dim3(512),  512, 0, stream>>>(Ab, qwT,  Qb,  nullptr, nullptr);
  conv_bf16<<<dim3(2048), 256, 0, stream>>>(y, Ab, 2097152);
  gemm_bt<1, 8><<<dim3(1024), 512, 0, stream>>>(Ab, kvwT, Kb,  Vtb,     nullptr);
  attn_kernel<<<dim3(1024), 512, 0, stream>>>(Qb, Kb, Vtb, Bm, Ab);
  gemm_bt<2, 4><<<dim3(512),  512, 0, stream>>>(Ab, pwT,  out, nullptr, proj_b);
}

// Round 8
// 373.113 us; speedup vs baseline: 1.0485x; 1.0485x over previous
//
#include <hip/hip_runtime.h>

typedef unsigned short u16;
typedef __attribute__((ext_vector_type(8))) short short8;
typedef __attribute__((ext_vector_type(4))) float floatx4;
typedef __attribute__((ext_vector_type(4))) unsigned short ushort4v;
typedef __attribute__((ext_vector_type(2))) unsigned int uint2v;

__device__ __forceinline__ float bf2f(u16 v){
  union { unsigned int u; float f; } x; x.u = ((unsigned int)v) << 16; return x.f;
}
__device__ __forceinline__ u16 f2bf(float f){
  union { float f; unsigned int u; } x; x.f = f;
  unsigned int r = x.u + 0x7FFFu + ((x.u >> 16) & 1u);
  return (u16)(r >> 16);
}
__device__ __forceinline__ short8 cvt8(float4 f0, float4 f1){
  short8 v;
  v[0] = (short)f2bf(f0.x); v[1] = (short)f2bf(f0.y);
  v[2] = (short)f2bf(f0.z); v[3] = (short)f2bf(f0.w);
  v[4] = (short)f2bf(f1.x); v[5] = (short)f2bf(f1.y);
  v[6] = (short)f2bf(f1.z); v[7] = (short)f2bf(f1.w);
  return v;
}

__device__ __forceinline__ void async16(const void* g, void* l){
  __builtin_amdgcn_global_load_lds(
      (__attribute__((address_space(1))) unsigned int*)const_cast<void*>(g),
      (__attribute__((address_space(3))) unsigned int*)l, 16, 0, 0);
}

// -------- fp32 -> bf16 bulk convert (memory-bound) --------------------------
__global__ __launch_bounds__(256)
void conv_bf16(const float* __restrict__ in, u16* __restrict__ out, int n8){
  const int stride = gridDim.x * 256;
  for (int i = blockIdx.x * 256 + threadIdx.x; i < n8; i += stride){
    float4 f0 = ((const float4*)in)[(size_t)i * 2];
    float4 f1 = ((const float4*)in)[(size_t)i * 2 + 1];
    *(short8*)(out + (size_t)i * 8) = cvt8(f0, f1);
  }
}

// -------- weight transpose: fp32 in [R][C] -> bf16 out [C][R] ---------------
__global__ void transpose_f32(const float* __restrict__ in, u16* __restrict__ out,
                              int R, int C){
  __shared__ u16 t[32][33];
  const int tx = threadIdx.x;
  const int c0 = blockIdx.x * 32, r0 = blockIdx.y * 32;
  for (int i = tx; i < 1024; i += 256){
    int r = i >> 5, c = i & 31;
    t[r][c] = f2bf(in[(size_t)(r0 + r) * C + c0 + c]);
  }
  __syncthreads();
  for (int i = tx; i < 1024; i += 256){
    int r = i >> 5, c = i & 31;
    out[(size_t)(c0 + r) * R + r0 + c] = t[c][r];
  }
}

// -------- expand relative-position bias -------------------------------------
// Layout [h][q][k] (q-major), values pre-scaled x8 (exact exponent shift):
//   0.125*(qk_raw + 8*b) == 0.125*qk_raw + b   (bit-identical)
__global__ void bias_expand(const float* __restrict__ table, u16* __restrict__ Bm){
  int i = blockIdx.x * 256 + threadIdx.x;   // 65536 (q,k) pairs, q major
  int q = i >> 8, k = i & 255;
  int rh = (q >> 4) - (k >> 4) + 15;
  int rw = (q & 15) - (k & 15) + 15;
  int idx = rh * 31 + rw;                   // [0, 960]
  #pragma unroll
  for (int h = 0; h < 8; h++)
    Bm[h * 65536 + i] = f2bf(8.0f * table[(size_t)idx * 8 + h]);
}

// ---------------- GEMM: C[M,N] = A[M,512] x Bt[N,512]^T ---------------------
// R8: K-loop = R7 (256x128 tile, BK=32, 8 waves, 3 slots 72 KB -> 2 blk/CU,
// counted vmcnt(3)). NEW: coalesced epilogue for MODE 0/1 via LDS regather —
// the old direct u16 scatter (V^T: lanes 512B apart -> ~64 L2 transactions
// per store instr, ~65k cycles/block of TA serialization; K/Q: 32B runs) is
// replaced by: acc -> LT[c][row] (cvt_pk + b64 writes) -> barrier -> fully
// coalesced 16B global stores (V: row-segments; K/Q: dd-gather per key-row).
// MODE 0: write Q permuted [b][h][n][d] (bf16)
// MODE 1: write K [b][h][n][d] and V^T [b][h][d][n] (bf16)
// MODE 2: write fp32 out[row][col] = v + proj_b[col]  (direct, 64B runs)
template<int MODE, int GX>
__global__ __launch_bounds__(512)
void gemm_bt(const u16* __restrict__ A, const u16* __restrict__ Bt,
             void* __restrict__ O0, u16* __restrict__ O1,
             const float* __restrict__ bias)
{
  // 72 KB staging pool, re-carved by the epilogue as LT[128][264] (67.6 KB)
  __shared__ __align__(16) u16 SMEM[3 * 256 * 32 + 3 * 128 * 32];
  u16* As = SMEM;                  // 3 slots of [256*32]
  u16* Bs = SMEM + 3 * 256 * 32;   // 3 slots of [128*32]
  const int tid  = threadIdx.x;
  const int lane = tid & 63, wave = tid >> 6;
  const int q16  = lane & 15, quad = lane >> 4;
  const int wr   = wave >> 1, wc = wave & 1;      // 4M x 2N wave tiles (64x64)

  constexpr int NWG = 128 * GX;
  constexpr int CPX = NWG / 8;
  const int bid = blockIdx.x;
  const int swz = (bid & 7) * CPX + (bid >> 3);   // bijective XCD swizzle
  const int rowBase = (swz / GX) * 256;
  const int colBase = (swz % GX) * 128;

  const u16* Ap = A  + (size_t)rowBase * 512;
  const u16* Bp = Bt + (size_t)colBase * 512;

  floatx4 acc[4][4];
  #pragma unroll
  for (int i = 0; i < 4; i++)
    #pragma unroll
    for (int j = 0; j < 4; j++) acc[i][j] = floatx4{0.f, 0.f, 0.f, 0.f};

  // staging geometry: granule g (16B) -> tile row g>>2, phys chunk g&3,
  // source chunk = phys ^ ((row>>1)&3)
  int sraA[2], scaA[2];
  #pragma unroll
  for (int j = 0; j < 2; j++){
    int g = tid + j * 512;
    sraA[j] = g >> 2;
    scaA[j] = ((g & 3) ^ ((sraA[j] >> 1) & 3)) * 8;
  }
  const int srB = tid >> 2;
  const int scB = ((tid & 3) ^ ((srB >> 1) & 3)) * 8;

  // per-tile staging: A = 2 async16/thread, B = 1 async16/thread (3 vmem ops)
  auto STAGE = [&](int slot, int kt){
    #pragma unroll
    for (int j = 0; j < 2; j++){
      u16* d = &As[slot * 8192 + (size_t)(j * 512 + wave * 64) * 8];
      async16(Ap + (size_t)sraA[j] * 512 + kt * 32 + scaA[j], d);
    }
    u16* d = &Bs[slot * 4096 + (size_t)(wave * 64) * 8];
    async16(Bp + (size_t)srB * 512 + kt * 32 + scB, d);
  };

  // prologue: two tiles in flight (6 outstanding vmem ops)
  STAGE(0, 0);
  STAGE(1, 1);

  #pragma unroll
  for (int kt = 0; kt < 16; kt++){                // K=512, BK=32
    const int cs = kt % 3;
    // tile kt complete when all but the newest 3 (tile kt+1) have retired
    if (kt < 15) asm volatile("s_waitcnt vmcnt(3)" ::: "memory");
    else         asm volatile("s_waitcnt vmcnt(0)" ::: "memory");
    __builtin_amdgcn_s_barrier();                 // publish slot cs; all waves
    __builtin_amdgcn_sched_barrier(0);            // done reading (kt+2)%3
    if (kt + 2 < 16) STAGE((kt + 2) % 3, kt + 2); // fill the freed slot
    __builtin_amdgcn_sched_barrier(0);            // pin issue-early

    __builtin_amdgcn_s_setprio(1);
    short8 af[4], bfr[4];
    #pragma unroll
    for (int mt = 0; mt < 4; mt++){
      int r  = wr * 64 + mt * 16 + q16;
      int ph = ((quad ^ ((r >> 1) & 3))) * 8;
      af[mt] = *(const short8*)(&As[cs * 8192 + r * 32 + ph]);
    }
    #pragma unroll
    for (int nt = 0; nt < 4; nt++){
      int r  = wc * 64 + nt * 16 + q16;
      int ph = ((quad ^ ((r >> 1) & 3))) * 8;
      bfr[nt] = *(const short8*)(&Bs[cs * 4096 + r * 32 + ph]);
    }
    #pragma unroll
    for (int mt = 0; mt < 4; mt++)
      #pragma unroll
      for (int nt = 0; nt < 4; nt++)
        acc[mt][nt] = __builtin_amdgcn_mfma_f32_16x16x32_bf16(
            af[mt], bfr[nt], acc[mt][nt], 0, 0, 0);
    __builtin_amdgcn_s_setprio(0);
  }

  if (MODE == 2){
    // fp32 direct store (lanes -> 64B runs, acceptable)
    #pragma unroll
    for (int mt = 0; mt < 4; mt++){
      #pragma unroll
      for (int nt = 0; nt < 4; nt++){
        const floatx4 v = acc[mt][nt];
        const int col = colBase + wc * 64 + nt * 16 + q16;
        #pragma unroll
        for (int r = 0; r < 4; r++){
          const int row = rowBase + wr * 64 + mt * 16 + quad * 4 + r;
          ((float*)O0)[(size_t)row * 512 + col] = v[r] + bias[col];
        }
      }
    }
  } else {
    // ---- coalesced epilogue: acc -> LT[c 128][row 256 (+8 pad)] -> global --
    __syncthreads();                       // staging LDS now dead, reuse it
    u16* LT = SMEM;                        // [128][264] u16 = 67.6 KB
    const int cw = wc * 64 + q16;          // local col for nt=0
    const int rw = wr * 64 + quad * 4;     // local row for mt=0, r=0
    #pragma unroll
    for (int nt = 0; nt < 4; nt++){
      #pragma unroll
      for (int mt = 0; mt < 4; mt++){
        const floatx4 v = acc[mt][nt];
        unsigned int w0, w1;
        asm("v_cvt_pk_bf16_f32 %0, %1, %2" : "=v"(w0) : "v"(v[0]), "v"(v[1]));
        asm("v_cvt_pk_bf16_f32 %0, %1, %2" : "=v"(w1) : "v"(v[2]), "v"(v[3]));
        uint2v p; p[0] = w0; p[1] = w1;    // rows rw+mt*16 .. +3, col cw+nt*16
        *(uint2v*)(&LT[(size_t)(cw + nt * 16) * 264 + rw + mt * 16]) = p;
      }
    }
    __syncthreads();
    const int bb = rowBase >> 8;           // rowBase multiple of 256 -> one b
    if (MODE == 1 && colBase >= 512){
      // V^T block: thread = (c, seg); write 128B row-segment, coalesced
      const int c = tid >> 2, seg = tid & 3;
      const int col = colBase + c;
      const int hh = (col >> 6) & 7, dd = col & 63;
      u16* dst = O1 + (((size_t)(bb * 8 + hh)) * 64 + dd) * 256 + seg * 64;
      const u16* src = &LT[(size_t)c * 264 + seg * 64];
      #pragma unroll
      for (int j = 0; j < 8; j++)
        *(short8*)(dst + j * 8) = *(const short8*)(src + j * 8);
    } else {
      // K / Q block: thread = (head-half, key); gather 64 dd, 128B store
      const int hp = tid >> 8, key = tid & 255;
      const int col0 = colBase + hp * 64;
      const int hh = (col0 >> 6) & 7;
      u16* dst = (u16*)O0 + (((size_t)(bb * 8 + hh)) * 256 + key) * 64;
      #pragma unroll
      for (int j = 0; j < 8; j++){
        union { u16 e[8]; short8 s; } t8;
        #pragma unroll
        for (int d2 = 0; d2 < 8; d2++)
          t8.e[d2] = LT[(size_t)(hp * 64 + j * 8 + d2) * 264 + key];
        *(short8*)(dst + j * 8) = t8.s;
      }
    }
  }
}

// ---------------- fused MFMA attention: one block per (b,h) -----------------
// R6 (kept): swapped-operand QK^T — acc[kt] = mfma(K_frag, Q_frag): each lane
// holds S[k = kt*16+quad*4+r][q = qbase+q16]. Softmax fully in-register:
// tree max/sum + 2 shfl_xor. P packed via v_cvt_pk_bf16_f32, redistributed
// to PV A-fragments with 8 shfl per K-step. No P LDS: Ks 32K + Vs 32K = 64K.
__global__ __launch_bounds__(512)
void attn_kernel(const u16* __restrict__ Qb, const u16* __restrict__ Kb,
                 const u16* __restrict__ Vtb, const u16* __restrict__ Bm,
                 u16* __restrict__ Ob)
{
  __shared__ __align__(16) u16 Ks[256 * 64];    // [k][d], 16B-chunk XOR swizzle
  __shared__ __align__(16) u16 Vs[64 * 256];    // [d][k], 16B-chunk XOR swizzle
  const int bh = blockIdx.x;
  const int b = bh >> 3, h = bh & 7;
  const u16* Qp = Qb  + (size_t)bh * 256 * 64;
  const u16* Kp = Kb  + (size_t)bh * 256 * 64;
  const u16* Vp = Vtb + (size_t)bh * 64 * 256;
  const u16* Bp = Bm  + (size_t)h * 65536;      // [q][k], pre-scaled x8
  const int tid = threadIdx.x;
  const int lane = tid & 63, wave = tid >> 6;
  const int q16 = lane & 15, quad = lane >> 4;

  // ---- stage K: 2048 granules of 16B; LDS linear, source pre-swizzled ----
  #pragma unroll
  for (int j = 0; j < 4; j++){
    int g = tid + j * 512;
    int row = g >> 3, phys = g & 7;             // 8 chunks per 64-elem row
    async16(Kp + row * 64 + ((phys ^ (row & 7)) * 8),
            &Ks[(size_t)(j * 512 + wave * 64) * 8]);
  }
  // ---- stage V: rows of 32 chunks ----
  #pragma unroll
  for (int j = 0; j < 4; j++){
    int g = tid + j * 512;
    int row = g >> 5, phys = g & 31;
    async16(Vp + row * 256 + ((phys ^ (row & 7)) * 8),
            &Vs[(size_t)(j * 512 + wave * 64) * 8]);
  }
  asm volatile("s_waitcnt vmcnt(4)" ::: "memory");  // this wave's K retired
  __builtin_amdgcn_s_barrier();                     // K visible to all waves

  // P-redistribution lane geometry (exchange among the 4 lanes sharing q16):
  // target quad t, step s needs words W[src quad' = 2(t&1)(+1)][kt = 2s+(t>>1)]
  const int la = q16 + ((quad & 1) << 5);       // lane of src quad' = 2(t&1)
  const int lb = la + 16;                       // lane of src quad' = 2(t&1)+1
  const bool hi = (quad >> 1) != 0;             // kt = 2s+1 half?

  for (int chunk = 0; chunk < 2; chunk++){
    const int qbase = wave * 32 + chunk * 16;
    const int qrow  = qbase + q16;
    const short8 qa0 = *(const short8*)(Qp + qrow * 64 + quad * 8);
    const short8 qa1 = *(const short8*)(Qp + qrow * 64 + 32 + quad * 8);

    // acc init = 8*bias at (q = qrow, k = kt*16 + quad*4 + r), r contiguous
    floatx4 acc[16];
    #pragma unroll
    for (int kt = 0; kt < 16; kt++){
      ushort4v bv = *(const ushort4v*)(Bp + (size_t)qrow * 256 + kt * 16 + quad * 4);
      floatx4 a;
      a[0] = bf2f(bv[0]); a[1] = bf2f(bv[1]);
      a[2] = bf2f(bv[2]); a[3] = bf2f(bv[3]);
      acc[kt] = a;
    }

    __builtin_amdgcn_s_setprio(1);
    #pragma unroll
    for (int kt = 0; kt < 16; kt++){
      const int row = kt * 16 + q16;
      const short8 k0 = *(const short8*)(&Ks[row * 64 + ((quad       ^ (row & 7)) * 8)]);
      const short8 k1 = *(const short8*)(&Ks[row * 64 + (((quad + 4) ^ (row & 7)) * 8)]);
      acc[kt] = __builtin_amdgcn_mfma_f32_16x16x32_bf16(k0, qa0, acc[kt], 0, 0, 0);
      acc[kt] = __builtin_amdgcn_mfma_f32_16x16x32_bf16(k1, qa1, acc[kt], 0, 0, 0);
    }
    __builtin_amdgcn_s_setprio(0);

    // ---- in-register row softmax (q fixed per lane) ----
    floatx4 m4 = acc[0];
    #pragma unroll
    for (int kt = 1; kt < 16; kt++){
      m4[0] = fmaxf(m4[0], acc[kt][0]);
      m4[1] = fmaxf(m4[1], acc[kt][1]);
      m4[2] = fmaxf(m4[2], acc[kt][2]);
      m4[3] = fmaxf(m4[3], acc[kt][3]);
    }
    float m = fmaxf(fmaxf(m4[0], m4[1]), fmaxf(m4[2], m4[3]));
    m = fmaxf(m, __shfl_xor(m, 16, 64));
    m = fmaxf(m, __shfl_xor(m, 32, 64));

    const float Cf = 0.125f * 1.4426950408889634f;   // scale * log2(e)
    unsigned int w[32];                              // packed bf16 pairs
    floatx4 l4 = {0.f, 0.f, 0.f, 0.f};
    #pragma unroll
    for (int kt = 0; kt < 16; kt++){
      float e0 = exp2f((acc[kt][0] - m) * Cf);
      float e1 = exp2f((acc[kt][1] - m) * Cf);
      float e2 = exp2f((acc[kt][2] - m) * Cf);
      float e3 = exp2f((acc[kt][3] - m) * Cf);
      l4[0] += e0; l4[1] += e1; l4[2] += e2; l4[3] += e3;
      asm("v_cvt_pk_bf16_f32 %0, %1, %2" : "=v"(w[2 * kt])     : "v"(e0), "v"(e1));
      asm("v_cvt_pk_bf16_f32 %0, %1, %2" : "=v"(w[2 * kt + 1]) : "v"(e2), "v"(e3));
    }
    float l = (l4[0] + l4[1]) + (l4[2] + l4[3]);
    l += __shfl_xor(l, 16, 64);
    l += __shfl_xor(l, 32, 64);
    const float rl = 1.0f / l;

    if (chunk == 0){
      asm volatile("s_waitcnt vmcnt(0)" ::: "memory"); // this wave's V retired
      __builtin_amdgcn_s_barrier();                    // V visible to all waves
    }

    // ---- PV: build A-fragment per 32-k step via 8 shfl, 4 mfma each ----
    floatx4 o[4];
    #pragma unroll
    for (int nt = 0; nt < 4; nt++) o[nt] = floatx4{0.f, 0.f, 0.f, 0.f};
    #pragma unroll
    for (int s = 0; s < 8; s++){
      int a0 = __shfl((int)w[4 * s + 0], la, 64);
      int a1 = __shfl((int)w[4 * s + 1], la, 64);
      int A0 = __shfl((int)w[4 * s + 2], la, 64);
      int A1 = __shfl((int)w[4 * s + 3], la, 64);
      int b0 = __shfl((int)w[4 * s + 0], lb, 64);
      int b1 = __shfl((int)w[4 * s + 1], lb, 64);
      int B0 = __shfl((int)w[4 * s + 2], lb, 64);
      int B1 = __shfl((int)w[4 * s + 3], lb, 64);
      union { int u[4]; short8 s8; } P;
      P.u[0] = hi ? A0 : a0;     // k = 32s + quad*8 + 0,1
      P.u[1] = hi ? A1 : a1;     // +2,3
      P.u[2] = hi ? B0 : b0;     // +4,5
      P.u[3] = hi ? B1 : b1;     // +6,7
      __builtin_amdgcn_s_setprio(1);
      #pragma unroll
      for (int nt = 0; nt < 4; nt++){
        const int row = nt * 16 + q16;
        const int c32 = s * 4 + quad;                  // 16B chunk in V row
        const short8 vb = *(const short8*)(&Vs[row * 256 + ((c32 ^ (row & 7)) * 8)]);
        o[nt] = __builtin_amdgcn_mfma_f32_16x16x32_bf16(P.s8, vb, o[nt], 0, 0, 0);
      }
      __builtin_amdgcn_s_setprio(0);
    }

    // rl lives at lane q16 = q-row; PV output rows are q = qbase+quad*4+r
    float rlr[4];
    #pragma unroll
    for (int r = 0; r < 4; r++) rlr[r] = __shfl(rl, quad * 4 + r, 64);
    #pragma unroll
    for (int nt = 0; nt < 4; nt++)
      #pragma unroll
      for (int r = 0; r < 4; r++){
        int q = qbase + quad * 4 + r;
        Ob[((size_t)(b * 256 + q)) * 512 + h * 64 + nt * 16 + q16] =
            f2bf(o[nt][r] * rlr[r]);
      }
  }
}

extern "C" void kernel_launch(void* const* d_in, const int* in_sizes, int n_in,
                              void* d_out, int out_size, void* d_ws, size_t ws_size,
                              hipStream_t stream)
{
  (void)in_sizes; (void)n_in; (void)out_size; (void)ws_size;
  const float* x      = (const float*)d_in[0];
  const float* y      = (const float*)d_in[1];
  const float* q_w    = (const float*)d_in[2];
  const float* kv_w   = (const float*)d_in[3];
  const float* proj_w = (const float*)d_in[4];
  const float* proj_b = (const float*)d_in[5];
  const float* btab   = (const float*)d_in[6];
  float* out = (float*)d_out;                   // fp32 output per reference
  char* w = (char*)d_ws;

  // workspace layout (total 137,363,456 B)
  u16* Qb   = (u16*)(w);                    // [B,H,256,64] bf16
  u16* Kb   = (u16*)(w + 33554432);         // [B,H,256,64]
  u16* Vtb  = (u16*)(w + 67108864);         // [B,H,64,256]
  u16* Ab   = (u16*)(w + 100663296);        // [B*N,512] bf16 (xb / yb / attn-out)
  u16* qwT  = (u16*)(w + 134217728);        // [512,512]
  u16* kvwT = (u16*)(w + 134742016);        // [1024,512]
  u16* pwT  = (u16*)(w + 135790592);        // [512,512]
  u16* Bm   = (u16*)(w + 136314880);        // [8,256,256] (x8, [h][q][k])

  transpose_f32<<<dim3(16, 16), 256, 0, stream>>>(q_w,    qwT,  512, 512);
  transpose_f32<<<dim3(32, 16), 256, 0, stream>>>(kv_w,   kvwT, 512, 1024);
  transpose_f32<<<dim3(16, 16), 256, 0, stream>>>(proj_w, pwT,  512, 512);
  bias_expand<<<dim3(256), 256, 0, stream>>>(btab, Bm);

  conv_bf16<<<dim3(2048), 256, 0, stream>>>(x, Ab, 2097152);
  gemm_bt<0, 4><<<dim3(512),  512, 0, stream>>>(Ab, qwT,  Qb,  nullptr, nullptr);
  conv_bf16<<<dim3(2048), 256, 0, stream>>>(y, Ab, 2097152);
  gemm_bt<1, 8><<<dim3(1024), 512, 0, stream>>>(Ab, kvwT, Kb,  Vtb,     nullptr);
  attn_kernel<<<dim3(1024), 512, 0, stream>>>(Qb, Kb, Vtb, Bm, Ab);
  gemm_bt<2, 4><<<dim3(512),  512, 0, stream>>>(Ab, pwT,  out, nullptr, proj_b);
}

// Round 10
// 358.021 us; speedup vs baseline: 1.0927x; 1.0422x over previous
//
#include <hip/hip_runtime.h>

typedef unsigned short u16;
typedef __attribute__((ext_vector_type(8))) short short8;
typedef __attribute__((ext_vector_type(4))) float floatx4;
typedef __attribute__((ext_vector_type(4))) unsigned short ushort4v;
typedef __attribute__((ext_vector_type(2))) unsigned int uint2v;

__device__ __forceinline__ float bf2f(u16 v){
  union { unsigned int u; float f; } x; x.u = ((unsigned int)v) << 16; return x.f;
}
__device__ __forceinline__ u16 f2bf(float f){
  union { float f; unsigned int u; } x; x.f = f;
  unsigned int r = x.u + 0x7FFFu + ((x.u >> 16) & 1u);
  return (u16)(r >> 16);
}
__device__ __forceinline__ short8 cvt8(float4 f0, float4 f1){
  short8 v;
  v[0] = (short)f2bf(f0.x); v[1] = (short)f2bf(f0.y);
  v[2] = (short)f2bf(f0.z); v[3] = (short)f2bf(f0.w);
  v[4] = (short)f2bf(f1.x); v[5] = (short)f2bf(f1.y);
  v[6] = (short)f2bf(f1.z); v[7] = (short)f2bf(f1.w);
  return v;
}

__device__ __forceinline__ void async16(const void* g, void* l){
  __builtin_amdgcn_global_load_lds(
      (__attribute__((address_space(1))) unsigned int*)const_cast<void*>(g),
      (__attribute__((address_space(3))) unsigned int*)l, 16, 0, 0);
}

// -------- fp32 -> bf16 bulk convert (memory-bound) --------------------------
__global__ __launch_bounds__(256)
void conv_bf16(const float* __restrict__ in, u16* __restrict__ out, int n8){
  const int stride = gridDim.x * 256;
  for (int i = blockIdx.x * 256 + threadIdx.x; i < n8; i += stride){
    float4 f0 = ((const float4*)in)[(size_t)i * 2];
    float4 f1 = ((const float4*)in)[(size_t)i * 2 + 1];
    *(short8*)(out + (size_t)i * 8) = cvt8(f0, f1);
  }
}

// -------- weight transpose: fp32 in [R][C] -> bf16 out [C][R] ---------------
__global__ void transpose_f32(const float* __restrict__ in, u16* __restrict__ out,
                              int R, int C){
  __shared__ u16 t[32][33];
  const int tx = threadIdx.x;
  const int c0 = blockIdx.x * 32, r0 = blockIdx.y * 32;
  for (int i = tx; i < 1024; i += 256){
    int r = i >> 5, c = i & 31;
    t[r][c] = f2bf(in[(size_t)(r0 + r) * C + c0 + c]);
  }
  __syncthreads();
  for (int i = tx; i < 1024; i += 256){
    int r = i >> 5, c = i & 31;
    out[(size_t)(c0 + r) * R + r0 + c] = t[c][r];
  }
}

// -------- expand relative-position bias -------------------------------------
// Layout [h][q][k] (q-major), values pre-scaled x8 (exact exponent shift):
//   0.125*(qk_raw + 8*b) == 0.125*qk_raw + b   (bit-identical)
__global__ void bias_expand(const float* __restrict__ table, u16* __restrict__ Bm){
  int i = blockIdx.x * 256 + threadIdx.x;   // 65536 (q,k) pairs, q major
  int q = i >> 8, k = i & 255;
  int rh = (q >> 4) - (k >> 4) + 15;
  int rw = (q & 15) - (k & 15) + 15;
  int idx = rh * 31 + rw;                   // [0, 960]
  #pragma unroll
  for (int h = 0; h < 8; h++)
    Bm[h * 65536 + i] = f2bf(8.0f * table[(size_t)idx * 8 + h]);
}

// ---------------- GEMM: C[M,N] = A[M,512] x Bt[N,512]^T ---------------------
// R8 (kept): K-loop 256x128 tile, BK=32, 8 waves, 3 slots 72 KB -> 2 blk/CU,
// counted vmcnt(3); coalesced epilogue for MODE 0/1 via LDS regather.
// MODE 0: write Q permuted [b][h][n][d] (bf16)
// MODE 1: write K [b][h][n][d] and V^T [b][h][d][n] (bf16)
// MODE 2: write fp32 out[row][col] = v + proj_b[col]  (direct, 64B runs)
template<int MODE, int GX>
__global__ __launch_bounds__(512)
void gemm_bt(const u16* __restrict__ A, const u16* __restrict__ Bt,
             void* __restrict__ O0, u16* __restrict__ O1,
             const float* __restrict__ bias)
{
  // 72 KB staging pool, re-carved by the epilogue as LT[128][264] (67.6 KB)
  __shared__ __align__(16) u16 SMEM[3 * 256 * 32 + 3 * 128 * 32];
  u16* As = SMEM;                  // 3 slots of [256*32]
  u16* Bs = SMEM + 3 * 256 * 32;   // 3 slots of [128*32]
  const int tid  = threadIdx.x;
  const int lane = tid & 63, wave = tid >> 6;
  const int q16  = lane & 15, quad = lane >> 4;
  const int wr   = wave >> 1, wc = wave & 1;      // 4M x 2N wave tiles (64x64)

  constexpr int NWG = 128 * GX;
  constexpr int CPX = NWG / 8;
  const int bid = blockIdx.x;
  const int swz = (bid & 7) * CPX + (bid >> 3);   // bijective XCD swizzle
  const int rowBase = (swz / GX) * 256;
  const int colBase = (swz % GX) * 128;

  const u16* Ap = A  + (size_t)rowBase * 512;
  const u16* Bp = Bt + (size_t)colBase * 512;

  floatx4 acc[4][4];
  #pragma unroll
  for (int i = 0; i < 4; i++)
    #pragma unroll
    for (int j = 0; j < 4; j++) acc[i][j] = floatx4{0.f, 0.f, 0.f, 0.f};

  // staging geometry: granule g (16B) -> tile row g>>2, phys chunk g&3,
  // source chunk = phys ^ ((row>>1)&3)
  int sraA[2], scaA[2];
  #pragma unroll
  for (int j = 0; j < 2; j++){
    int g = tid + j * 512;
    sraA[j] = g >> 2;
    scaA[j] = ((g & 3) ^ ((sraA[j] >> 1) & 3)) * 8;
  }
  const int srB = tid >> 2;
  const int scB = ((tid & 3) ^ ((srB >> 1) & 3)) * 8;

  // per-tile staging: A = 2 async16/thread, B = 1 async16/thread (3 vmem ops)
  auto STAGE = [&](int slot, int kt){
    #pragma unroll
    for (int j = 0; j < 2; j++){
      u16* d = &As[slot * 8192 + (size_t)(j * 512 + wave * 64) * 8];
      async16(Ap + (size_t)sraA[j] * 512 + kt * 32 + scaA[j], d);
    }
    u16* d = &Bs[slot * 4096 + (size_t)(wave * 64) * 8];
    async16(Bp + (size_t)srB * 512 + kt * 32 + scB, d);
  };

  // prologue: two tiles in flight (6 outstanding vmem ops)
  STAGE(0, 0);
  STAGE(1, 1);

  #pragma unroll
  for (int kt = 0; kt < 16; kt++){                // K=512, BK=32
    const int cs = kt % 3;
    // tile kt complete when all but the newest 3 (tile kt+1) have retired
    if (kt < 15) asm volatile("s_waitcnt vmcnt(3)" ::: "memory");
    else         asm volatile("s_waitcnt vmcnt(0)" ::: "memory");
    __builtin_amdgcn_s_barrier();                 // publish slot cs; all waves
    __builtin_amdgcn_sched_barrier(0);            // done reading (kt+2)%3
    if (kt + 2 < 16) STAGE((kt + 2) % 3, kt + 2); // fill the freed slot
    __builtin_amdgcn_sched_barrier(0);            // pin issue-early

    __builtin_amdgcn_s_setprio(1);
    short8 af[4], bfr[4];
    #pragma unroll
    for (int mt = 0; mt < 4; mt++){
      int r  = wr * 64 + mt * 16 + q16;
      int ph = ((quad ^ ((r >> 1) & 3))) * 8;
      af[mt] = *(const short8*)(&As[cs * 8192 + r * 32 + ph]);
    }
    #pragma unroll
    for (int nt = 0; nt < 4; nt++){
      int r  = wc * 64 + nt * 16 + q16;
      int ph = ((quad ^ ((r >> 1) & 3))) * 8;
      bfr[nt] = *(const short8*)(&Bs[cs * 4096 + r * 32 + ph]);
    }
    #pragma unroll
    for (int mt = 0; mt < 4; mt++)
      #pragma unroll
      for (int nt = 0; nt < 4; nt++)
        acc[mt][nt] = __builtin_amdgcn_mfma_f32_16x16x32_bf16(
            af[mt], bfr[nt], acc[mt][nt], 0, 0, 0);
    __builtin_amdgcn_s_setprio(0);
  }

  if (MODE == 2){
    // fp32 direct store (lanes -> 64B runs, acceptable)
    #pragma unroll
    for (int mt = 0; mt < 4; mt++){
      #pragma unroll
      for (int nt = 0; nt < 4; nt++){
        const floatx4 v = acc[mt][nt];
        const int col = colBase + wc * 64 + nt * 16 + q16;
        #pragma unroll
        for (int r = 0; r < 4; r++){
          const int row = rowBase + wr * 64 + mt * 16 + quad * 4 + r;
          ((float*)O0)[(size_t)row * 512 + col] = v[r] + bias[col];
        }
      }
    }
  } else {
    // ---- coalesced epilogue: acc -> LT[c 128][row 256 (+8 pad)] -> global --
    __syncthreads();                       // staging LDS now dead, reuse it
    u16* LT = SMEM;                        // [128][264] u16 = 67.6 KB
    const int cw = wc * 64 + q16;          // local col for nt=0
    const int rw = wr * 64 + quad * 4;     // local row for mt=0, r=0
    #pragma unroll
    for (int nt = 0; nt < 4; nt++){
      #pragma unroll
      for (int mt = 0; mt < 4; mt++){
        const floatx4 v = acc[mt][nt];
        unsigned int w0, w1;
        asm("v_cvt_pk_bf16_f32 %0, %1, %2" : "=v"(w0) : "v"(v[0]), "v"(v[1]));
        asm("v_cvt_pk_bf16_f32 %0, %1, %2" : "=v"(w1) : "v"(v[2]), "v"(v[3]));
        uint2v p; p[0] = w0; p[1] = w1;    // rows rw+mt*16 .. +3, col cw+nt*16
        *(uint2v*)(&LT[(size_t)(cw + nt * 16) * 264 + rw + mt * 16]) = p;
      }
    }
    __syncthreads();
    const int bb = rowBase >> 8;           // rowBase multiple of 256 -> one b
    if (MODE == 1 && colBase >= 512){
      // V^T block: thread = (c, seg); write 128B row-segment, coalesced
      const int c = tid >> 2, seg = tid & 3;
      const int col = colBase + c;
      const int hh = (col >> 6) & 7, dd = col & 63;
      u16* dst = O1 + (((size_t)(bb * 8 + hh)) * 64 + dd) * 256 + seg * 64;
      const u16* src = &LT[(size_t)c * 264 + seg * 64];
      #pragma unroll
      for (int j = 0; j < 8; j++)
        *(short8*)(dst + j * 8) = *(const short8*)(src + j * 8);
    } else {
      // K / Q block: thread = (head-half, key); gather 64 dd, 128B store
      const int hp = tid >> 8, key = tid & 255;
      const int col0 = colBase + hp * 64;
      const int hh = (col0 >> 6) & 7;
      u16* dst = (u16*)O0 + (((size_t)(bb * 8 + hh)) * 256 + key) * 64;
      #pragma unroll
      for (int j = 0; j < 8; j++){
        union { u16 e[8]; short8 s; } t8;
        #pragma unroll
        for (int d2 = 0; d2 < 8; d2++)
          t8.e[d2] = LT[(size_t)(hp * 64 + j * 8 + d2) * 264 + key];
        *(short8*)(dst + j * 8) = t8.s;
      }
    }
  }
}

// ---------------- fused MFMA attention: one block per (b,h) -----------------
// R10: R8 structure + (a) Q loads for BOTH chunks hoisted before the K/V
// async16s (sched_barrier-pinned order Q(4),K(4),V(4); vmcnt(4) = Q+K
// retired, V outstanding); (b) exp2 fma-fold (2 VALU/elem, was 3); (c) chunk
// loop explicitly unrolled so qa[chunk][.] indices are compile-time (rule
// #20: runtime-indexed reg arrays spill to scratch).
__global__ __launch_bounds__(512)
void attn_kernel(const u16* __restrict__ Qb, const u16* __restrict__ Kb,
                 const u16* __restrict__ Vtb, const u16* __restrict__ Bm,
                 u16* __restrict__ Ob)
{
  __shared__ __align__(16) u16 Ks[256 * 64];    // [k][d], 16B-chunk XOR swizzle
  __shared__ __align__(16) u16 Vs[64 * 256];    // [d][k], 16B-chunk XOR swizzle
  const int bh = blockIdx.x;
  const int b = bh >> 3, h = bh & 7;
  const u16* Qp = Qb  + (size_t)bh * 256 * 64;
  const u16* Kp = Kb  + (size_t)bh * 256 * 64;
  const u16* Vp = Vtb + (size_t)bh * 64 * 256;
  const u16* Bp = Bm  + (size_t)h * 65536;      // [q][k], pre-scaled x8
  const int tid = threadIdx.x;
  const int lane = tid & 63, wave = tid >> 6;
  const int q16 = lane & 15, quad = lane >> 4;

  // ---- hoisted Q loads (both chunks): issued BEFORE the asyncs ----
  const int qrow0 = wave * 32 + q16;
  short8 qa[2][2];
  qa[0][0] = *(const short8*)(Qp + qrow0 * 64 + quad * 8);
  qa[0][1] = *(const short8*)(Qp + qrow0 * 64 + 32 + quad * 8);
  qa[1][0] = *(const short8*)(Qp + (qrow0 + 16) * 64 + quad * 8);
  qa[1][1] = *(const short8*)(Qp + (qrow0 + 16) * 64 + 32 + quad * 8);
  __builtin_amdgcn_sched_barrier(0);

  // ---- stage K: 2048 granules of 16B; LDS linear, source pre-swizzled ----
  #pragma unroll
  for (int j = 0; j < 4; j++){
    int g = tid + j * 512;
    int row = g >> 3, phys = g & 7;
    async16(Kp + row * 64 + ((phys ^ (row & 7)) * 8),
            &Ks[(size_t)(j * 512 + wave * 64) * 8]);
  }
  __builtin_amdgcn_sched_barrier(0);
  // ---- stage V: rows of 32 chunks ----
  #pragma unroll
  for (int j = 0; j < 4; j++){
    int g = tid + j * 512;
    int row = g >> 5, phys = g & 31;
    async16(Vp + row * 256 + ((phys ^ (row & 7)) * 8),
            &Vs[(size_t)(j * 512 + wave * 64) * 8]);
  }
  __builtin_amdgcn_sched_barrier(0);
  asm volatile("s_waitcnt vmcnt(4)" ::: "memory");  // Q + K retired, V out
  __builtin_amdgcn_s_barrier();                     // K visible to all waves

  // P-redistribution lane geometry (exchange among the 4 lanes sharing q16)
  const int la = q16 + ((quad & 1) << 5);
  const int lb = la + 16;
  const bool hi = (quad >> 1) != 0;

  #pragma unroll
  for (int chunk = 0; chunk < 2; chunk++){
    const int qbase = wave * 32 + chunk * 16;
    const int qrow  = qbase + q16;

    // acc init = 8*bias at (q = qrow, k = kt*16 + quad*4 + r), r contiguous
    floatx4 acc[16];
    #pragma unroll
    for (int kt = 0; kt < 16; kt++){
      ushort4v bv = *(const ushort4v*)(Bp + (size_t)qrow * 256 + kt * 16 + quad * 4);
      floatx4 a;
      a[0] = bf2f(bv[0]); a[1] = bf2f(bv[1]);
      a[2] = bf2f(bv[2]); a[3] = bf2f(bv[3]);
      acc[kt] = a;
    }

    __builtin_amdgcn_s_setprio(1);
    #pragma unroll
    for (int kt = 0; kt < 16; kt++){
      const int row = kt * 16 + q16;
      const short8 k0 = *(const short8*)(&Ks[row * 64 + ((quad       ^ (row & 7)) * 8)]);
      const short8 k1 = *(const short8*)(&Ks[row * 64 + (((quad + 4) ^ (row & 7)) * 8)]);
      acc[kt] = __builtin_amdgcn_mfma_f32_16x16x32_bf16(k0, qa[chunk][0], acc[kt], 0, 0, 0);
      acc[kt] = __builtin_amdgcn_mfma_f32_16x16x32_bf16(k1, qa[chunk][1], acc[kt], 0, 0, 0);
    }
    __builtin_amdgcn_s_setprio(0);

    // ---- in-register row softmax (q fixed per lane) ----
    floatx4 m4 = acc[0];
    #pragma unroll
    for (int kt = 1; kt < 16; kt++){
      m4[0] = fmaxf(m4[0], acc[kt][0]);
      m4[1] = fmaxf(m4[1], acc[kt][1]);
      m4[2] = fmaxf(m4[2], acc[kt][2]);
      m4[3] = fmaxf(m4[3], acc[kt][3]);
    }
    float m = fmaxf(fmaxf(m4[0], m4[1]), fmaxf(m4[2], m4[3]));
    m = fmaxf(m, __shfl_xor(m, 16, 64));
    m = fmaxf(m, __shfl_xor(m, 32, 64));

    const float Cf = 0.125f * 1.4426950408889634f;   // scale * log2(e)
    const float nmC = -m * Cf;
    unsigned int w[32];                              // packed bf16 pairs
    floatx4 l4 = {0.f, 0.f, 0.f, 0.f};
    #pragma unroll
    for (int kt = 0; kt < 16; kt++){
      float e0 = exp2f(fmaf(acc[kt][0], Cf, nmC));
      float e1 = exp2f(fmaf(acc[kt][1], Cf, nmC));
      float e2 = exp2f(fmaf(acc[kt][2], Cf, nmC));
      float e3 = exp2f(fmaf(acc[kt][3], Cf, nmC));
      l4[0] += e0; l4[1] += e1; l4[2] += e2; l4[3] += e3;
      asm("v_cvt_pk_bf16_f32 %0, %1, %2" : "=v"(w[2 * kt])     : "v"(e0), "v"(e1));
      asm("v_cvt_pk_bf16_f32 %0, %1, %2" : "=v"(w[2 * kt + 1]) : "v"(e2), "v"(e3));
    }
    float l = (l4[0] + l4[1]) + (l4[2] + l4[3]);
    l += __shfl_xor(l, 16, 64);
    l += __shfl_xor(l, 32, 64);
    const float rl = 1.0f / l;

    if (chunk == 0){
      asm volatile("s_waitcnt vmcnt(0)" ::: "memory"); // V retired
      __builtin_amdgcn_s_barrier();                    // V visible to all
    }

    // ---- PV: build A-fragment per 32-k step via 8 shfl, 4 mfma each ----
    floatx4 o[4];
    #pragma unroll
    for (int nt = 0; nt < 4; nt++) o[nt] = floatx4{0.f, 0.f, 0.f, 0.f};
    #pragma unroll
    for (int s = 0; s < 8; s++){
      int a0 = __shfl((int)w[4 * s + 0], la, 64);
      int a1 = __shfl((int)w[4 * s + 1], la, 64);
      int A0 = __shfl((int)w[4 * s + 2], la, 64);
      int A1 = __shfl((int)w[4 * s + 3], la, 64);
      int b0 = __shfl((int)w[4 * s + 0], lb, 64);
      int b1 = __shfl((int)w[4 * s + 1], lb, 64);
      int B0 = __shfl((int)w[4 * s + 2], lb, 64);
      int B1 = __shfl((int)w[4 * s + 3], lb, 64);
      union { int u[4]; short8 s8; } P;
      P.u[0] = hi ? A0 : a0;     // k = 32s + quad*8 + 0,1
      P.u[1] = hi ? A1 : a1;     // +2,3
      P.u[2] = hi ? B0 : b0;     // +4,5
      P.u[3] = hi ? B1 : b1;     // +6,7
      __builtin_amdgcn_s_setprio(1);
      #pragma unroll
      for (int nt = 0; nt < 4; nt++){
        const int row = nt * 16 + q16;
        const int c32 = s * 4 + quad;
        const short8 vb = *(const short8*)(&Vs[row * 256 + ((c32 ^ (row & 7)) * 8)]);
        o[nt] = __builtin_amdgcn_mfma_f32_16x16x32_bf16(P.s8, vb, o[nt], 0, 0, 0);
      }
      __builtin_amdgcn_s_setprio(0);
    }

    // rl lives at lane q16 = q-row; PV output rows are q = qbase+quad*4+r
    float rlr[4];
    #pragma unroll
    for (int r = 0; r < 4; r++) rlr[r] = __shfl(rl, quad * 4 + r, 64);
    #pragma unroll
    for (int nt = 0; nt < 4; nt++)
      #pragma unroll
      for (int r = 0; r < 4; r++){
        int q = qbase + quad * 4 + r;
        Ob[((size_t)(b * 256 + q)) * 512 + h * 64 + nt * 16 + q16] =
            f2bf(o[nt][r] * rlr[r]);
      }
  }
}

extern "C" void kernel_launch(void* const* d_in, const int* in_sizes, int n_in,
                              void* d_out, int out_size, void* d_ws, size_t ws_size,
                              hipStream_t stream)
{
  (void)in_sizes; (void)n_in; (void)out_size; (void)ws_size;
  const float* x      = (const float*)d_in[0];
  const float* y      = (const float*)d_in[1];
  const float* q_w    = (const float*)d_in[2];
  const float* kv_w   = (const float*)d_in[3];
  const float* proj_w = (const float*)d_in[4];
  const float* proj_b = (const float*)d_in[5];
  const float* btab   = (const float*)d_in[6];
  float* out = (float*)d_out;                   // fp32 output per reference
  char* w = (char*)d_ws;

  // workspace layout (total 137,363,456 B)
  u16* Qb   = (u16*)(w);                    // [B,H,256,64] bf16
  u16* Kb   = (u16*)(w + 33554432);         // [B,H,256,64]
  u16* Vtb  = (u16*)(w + 67108864);         // [B,H,64,256]
  u16* Ab   = (u16*)(w + 100663296);        // [B*N,512] bf16 (xb / yb / attn-out)
  u16* qwT  = (u16*)(w + 134217728);        // [512,512]
  u16* kvwT = (u16*)(w + 134742016);        // [1024,512]
  u16* pwT  = (u16*)(w + 135790592);        // [512,512]
  u16* Bm   = (u16*)(w + 136314880);        // [8,256,256] (x8, [h][q][k])

  transpose_f32<<<dim3(16, 16), 256, 0, stream>>>(q_w,    qwT,  512, 512);
  transpose_f32<<<dim3(32, 16), 256, 0, stream>>>(kv_w,   kvwT, 512, 1024);
  transpose_f32<<<dim3(16, 16), 256, 0, stream>>>(proj_w, pwT,  512, 512);
  bias_expand<<<dim3(256), 256, 0, stream>>>(btab, Bm);

  conv_bf16<<<dim3(2048), 256, 0, stream>>>(x, Ab, 2097152);
  gemm_bt<0, 4><<<dim3(512),  512, 0, stream>>>(Ab, qwT,  Qb,  nullptr, nullptr);
  conv_bf16<<<dim3(2048), 256, 0, stream>>>(y, Ab, 2097152);
  gemm_bt<1, 8><<<dim3(1024), 512, 0, stream>>>(Ab, kvwT, Kb,  Vtb,     nullptr);
  attn_kernel<<<dim3(1024), 512, 0, stream>>>(Qb, Kb, Vtb, Bm, Ab);
  gemm_bt<2, 4><<<dim3(512),  512, 0, stream>>>(Ab, pwT,  out, nullptr, proj_b);
}